// Round 8
// baseline (562.994 us; speedup 1.0000x reference)
//
#include <hip/hip_runtime.h>
#include <hip/hip_fp16.h>

#define DD 32
#define HH 8
#define ALPHA 0.01f
#define REC 24            // dwords per record: 8 x f32 ex + 32 x f16 hidden = 96B
#define SCAN_T 256
#define SCAN_E 1024       // elements scanned per block (4 per thread)

__global__ __launch_bounds__(256) void k_zero(int* __restrict__ cnt, int N) {
    int i = blockIdx.x * 256 + threadIdx.x;
    if (i < N) cnt[i] = 0;
}

__global__ __launch_bounds__(256) void k_count(const int* __restrict__ dst, int E,
                                               int* __restrict__ cnt) {
    int e = blockIdx.x * 256 + threadIdx.x;
    if (e < E) atomicAdd(&cnt[dst[e]], 1);
}

// per-block sums of cnt (SCAN_E elements per block)
__global__ __launch_bounds__(SCAN_T) void k_scan1(const int* __restrict__ cnt, int N,
                                                  int* __restrict__ bsum) {
    __shared__ int sh[SCAN_T];
    int t = threadIdx.x, b = blockIdx.x;
    int base = b * SCAN_E + t * 4;
    int s = 0;
    #pragma unroll
    for (int k = 0; k < 4; k++) { int i = base + k; if (i < N) s += cnt[i]; }
    sh[t] = s; __syncthreads();
    for (int off = SCAN_T / 2; off > 0; off >>= 1) {
        if (t < off) sh[t] += sh[t + off];
        __syncthreads();
    }
    if (t == 0) bsum[b] = sh[0];
}

// exclusive scan of block sums (nb <= SCAN_T), single block
__global__ __launch_bounds__(SCAN_T) void k_scan2(const int* __restrict__ bsum, int nb,
                                                  int* __restrict__ boff) {
    __shared__ int sh[SCAN_T];
    int t = threadIdx.x;
    int x = (t < nb) ? bsum[t] : 0;
    sh[t] = x; __syncthreads();
    for (int off = 1; off < SCAN_T; off <<= 1) {
        int v = (t >= off) ? sh[t - off] : 0;
        __syncthreads();
        sh[t] += v;
        __syncthreads();
    }
    if (t < nb) boff[t] = sh[t] - x;   // exclusive
}

// exclusive scan within each block + boff -> row_ptr
__global__ __launch_bounds__(SCAN_T) void k_scan3(const int* __restrict__ cnt, int N, int E,
                                                  const int* __restrict__ boff,
                                                  int* __restrict__ row_ptr) {
    __shared__ int sh[SCAN_T];
    int t = threadIdx.x, b = blockIdx.x;
    int base = b * SCAN_E + t * 4;
    int c[4];
    #pragma unroll
    for (int k = 0; k < 4; k++) { int i = base + k; c[k] = (i < N) ? cnt[i] : 0; }
    int ts = c[0] + c[1] + c[2] + c[3];
    sh[t] = ts; __syncthreads();
    for (int off = 1; off < SCAN_T; off <<= 1) {
        int v = (t >= off) ? sh[t - off] : 0;
        __syncthreads();
        sh[t] += v;
        __syncthreads();
    }
    int rp = boff[b] + sh[t] - ts;      // exclusive prefix for this thread's 4 elems
    int acc = 0;
    #pragma unroll
    for (int k = 0; k < 4; k++) {
        int i = base + k;
        if (i < N) row_ptr[i] = rp + acc;
        acc += c[k];
    }
    if (b == 0 && t == 0) row_ptr[N] = E;
}

// Per-edge: all 24 float4 loads issued up front (one HBM round-trip), l2norms,
// TransE encode, exp(leakyrelu(h.attn)), packed 96B record scattered into the
// destination node's CSR bucket. No softmax max-pass (logits bounded, f32 safe).
__global__ __launch_bounds__(256) void k_edge(
    const float* __restrict__ f0, const float* __restrict__ f1, const float* __restrict__ f2,
    const float* __restrict__ rv, const float* __restrict__ attn,
    const int* __restrict__ dst, int E,
    const int* __restrict__ row_ptr, int* __restrict__ cnt,
    float* __restrict__ records)
{
    __shared__ float4 s_attn[HH * 8];   // [q*8+i] = attn[q][4i..4i+3]
    __shared__ float s_R[DD];
    int t = threadIdx.x;
    if (t < 64) s_attn[t] = ((const float4*)attn)[t];
    if (t >= 64 && t < 96) {
        int d = t - 64;
        s_R[d] = rv[d] + 2.0f * (rv[DD + d] + rv[2 * DD + d]);
    }
    __syncthreads();

    int e = blockIdx.x * 256 + t;
    if (e >= E) return;

    // issue slot acquisition early; latency hides under the feature loads
    int n = dst[e];
    int rp0 = row_ptr[n];
    int r = atomicAdd(&cnt[n], -1) - 1;    // unique cursor in [0, deg)

    // issue ALL feature loads before any dependent compute
    const float4* p0 = (const float4*)(f0 + (size_t)e * DD);
    const float4* p1 = (const float4*)(f1 + (size_t)e * DD);
    const float4* p2 = (const float4*)(f2 + (size_t)e * DD);
    float4 a0[8], a1[8], a2[8];
    #pragma unroll
    for (int i = 0; i < 8; i++) a0[i] = p0[i];
    #pragma unroll
    for (int i = 0; i < 8; i++) a1[i] = p1[i];
    #pragma unroll
    for (int i = 0; i < 8; i++) a2[i] = p2[i];

    float s0 = 0.f, s1 = 0.f, s2 = 0.f;
    #pragma unroll
    for (int i = 0; i < 8; i++) {
        s0 += a0[i].x*a0[i].x + a0[i].y*a0[i].y + a0[i].z*a0[i].z + a0[i].w*a0[i].w;
        s1 += a1[i].x*a1[i].x + a1[i].y*a1[i].y + a1[i].z*a1[i].z + a1[i].w*a1[i].w;
        s2 += a2[i].x*a2[i].x + a2[i].y*a2[i].y + a2[i].z*a2[i].z + a2[i].w*a2[i].w;
    }
    float i0 = 1.0f / fmaxf(sqrtf(s0), 1e-12f);
    float i1 = 1.0f / fmaxf(sqrtf(s1), 1e-12f);
    float i2 = 1.0f / fmaxf(sqrtf(s2), 1e-12f);

    union HU { float4 v4[8]; float s[DD]; } h;
    #pragma unroll
    for (int i = 0; i < 8; i++) {
        h.v4[i].x = (a0[i].x*i0 + a1[i].x*i1 + a2[i].x*i2 + s_R[4*i+0]) * (1.0f/3.0f);
        h.v4[i].y = (a0[i].y*i0 + a1[i].y*i1 + a2[i].y*i2 + s_R[4*i+1]) * (1.0f/3.0f);
        h.v4[i].z = (a0[i].z*i0 + a1[i].z*i1 + a2[i].z*i2 + s_R[4*i+2]) * (1.0f/3.0f);
        h.v4[i].w = (a0[i].w*i0 + a1[i].w*i1 + a2[i].w*i2 + s_R[4*i+3]) * (1.0f/3.0f);
    }

    // logits -> exp (no max subtraction; |logit| bounded by |h||attn| ~ 25)
    float ex[HH];
    #pragma unroll
    for (int q = 0; q < HH; q++) {
        float acc = 0.0f;
        #pragma unroll
        for (int i = 0; i < 8; i++) {
            float4 w = s_attn[q * 8 + i];
            float4 x = h.v4[i];
            acc += x.x*w.x + x.y*w.y + x.z*w.z + x.w*w.w;
        }
        float a = acc > 0.0f ? acc : ALPHA * acc;
        ex[q] = __expf(a);
    }

    // pack record: 8 x f32 ex + 32 x f16 hidden = 6 float4 stores, contiguous 96B
    union PU { __half2 h2[16]; float4 f4[4]; } u;
    #pragma unroll
    for (int i = 0; i < 16; i++) u.h2[i] = __floats2half2_rn(h.s[2*i], h.s[2*i+1]);

    float* recp = records + (size_t)(rp0 + r) * REC;
    float4* rq = (float4*)recp;
    rq[0] = make_float4(ex[0], ex[1], ex[2], ex[3]);
    rq[1] = make_float4(ex[4], ex[5], ex[6], ex[7]);
    #pragma unroll
    for (int i = 0; i < 4; i++) rq[2 + i] = u.f4[i];
}

// One wave per node: sequential read of the node's CSR records, accumulate
// numerator + denominator in registers, one coalesced write. No atomics.
__global__ __launch_bounds__(256) void k_agg(
    const float* __restrict__ records, const int* __restrict__ row_ptr,
    float* __restrict__ out, int N)
{
    int wid = threadIdx.x >> 6, lane = threadIdx.x & 63;
    int n = blockIdx.x * 4 + wid;
    if (n >= N) return;
    int r0 = row_ptr[n], r1 = row_ptr[n + 1];
    int deg = r1 - r0;
    int d = lane & 31;
    int hq = lane >> 5;                  // half-wave owns heads hq*4 .. hq*4+3

    float ssum[4] = {0.f, 0.f, 0.f, 0.f};
    float acc[4]  = {0.f, 0.f, 0.f, 0.f};
    const float* rec = records + (size_t)r0 * REC;

    int j = 0;
    for (; j + 1 < deg; j += 2) {        // 2-deep: both records' loads in flight
        const float* ra = rec + (size_t)j * REC;
        const float* rb = ra + REC;
        float4 xa = *(const float4*)(ra + hq * 4);
        float  ha = __half2float(((const __half*)(ra + 8))[d]);
        float4 xb = *(const float4*)(rb + hq * 4);
        float  hb = __half2float(((const __half*)(rb + 8))[d]);
        ssum[0] += xa.x; ssum[1] += xa.y; ssum[2] += xa.z; ssum[3] += xa.w;
        acc[0] += xa.x * ha; acc[1] += xa.y * ha; acc[2] += xa.z * ha; acc[3] += xa.w * ha;
        ssum[0] += xb.x; ssum[1] += xb.y; ssum[2] += xb.z; ssum[3] += xb.w;
        acc[0] += xb.x * hb; acc[1] += xb.y * hb; acc[2] += xb.z * hb; acc[3] += xb.w * hb;
    }
    if (j < deg) {
        const float* ra = rec + (size_t)j * REC;
        float4 xa = *(const float4*)(ra + hq * 4);
        float  ha = __half2float(((const __half*)(ra + 8))[d]);
        ssum[0] += xa.x; ssum[1] += xa.y; ssum[2] += xa.z; ssum[3] += xa.w;
        acc[0] += xa.x * ha; acc[1] += xa.y * ha; acc[2] += xa.z * ha; acc[3] += xa.w * ha;
    }

    size_t ob = (size_t)n * (HH * DD) + hq * 128 + d;   // out idx = (hq*4+k)*32 + d
    #pragma unroll
    for (int k = 0; k < 4; k++) {
        float sv = ssum[k];
        float rr = sv > 0.0f ? 1.0f / sv : 0.0f;
        out[ob + k * 32] = acc[k] * rr;
    }
}

extern "C" void kernel_launch(void* const* d_in, const int* in_sizes, int n_in,
                              void* d_out, int out_size, void* d_ws, size_t ws_size,
                              hipStream_t stream)
{
    const float* f0   = (const float*)d_in[0];
    const float* f1   = (const float*)d_in[1];
    const float* f2   = (const float*)d_in[2];
    const float* rv   = (const float*)d_in[3];
    const float* attn = (const float*)d_in[4];
    const int*   dst  = (const int*)d_in[5];
    int E = in_sizes[0] / DD;
    int N = out_size / (HH * DD);
    float* out = (float*)d_out;

    auto al = [](size_t x) { return (x + 255) & ~(size_t)255; };
    char* w = (char*)d_ws;
    size_t off = 0;
    float* records = (float*)(w + off); off += al((size_t)E * REC * 4);
    int* row_ptr   = (int*)(w + off);   off += al(((size_t)N + 1) * 4);
    int* cnt       = (int*)(w + off);   off += al((size_t)N * 4);
    int* bsum      = (int*)(w + off);   off += al((size_t)SCAN_T * 4);
    int* boff      = (int*)(w + off);   off += al((size_t)SCAN_T * 4);
    (void)ws_size; (void)n_in;

    int nb = (N + SCAN_E - 1) / SCAN_E;      // 98 for N=100k (must be <= SCAN_T)

    k_zero<<<(N + 255) / 256, 256, 0, stream>>>(cnt, N);
    int gridE = (E + 255) / 256;
    k_count<<<gridE, 256, 0, stream>>>(dst, E, cnt);
    k_scan1<<<nb, SCAN_T, 0, stream>>>(cnt, N, bsum);
    k_scan2<<<1, SCAN_T, 0, stream>>>(bsum, nb, boff);
    k_scan3<<<nb, SCAN_T, 0, stream>>>(cnt, N, E, boff, row_ptr);
    k_edge<<<gridE, 256, 0, stream>>>(f0, f1, f2, rv, attn, dst, E, row_ptr, cnt, records);
    k_agg<<<(N + 3) / 4, 256, 0, stream>>>(records, row_ptr, out, N);
}